// Round 6
// baseline (183.100 us; speedup 1.0000x reference)
//
#include <hip/hip_runtime.h>

#define NN 100000
#define NE 1000000
#define OUT_D 64
#define EPS 1e-5f

#define NB 196         // buckets of 512 destination cols: 196*512 = 100352 >= NN
#define COLS 512
#define BSTRIDE 6016   // per-bucket capacity: mean 5120, +12.6 sigma
#define EPB 4096       // edges per part-block
#define NBLK1 245      // part blocks = ceil(NE/EPB)
#define NPROJ 1024     // proj blocks fused behind part
#define QCOLS 128      // out_kernel: quarter-bucket width
#define QCAP 1792      // per-quarter capacity: mean 1280, +14 sigma

typedef __attribute__((ext_vector_type(8))) short bf16x8;
typedef __attribute__((ext_vector_type(4))) float f32x4;

static __device__ __forceinline__ unsigned short f2bf(float f) {   // RNE
    unsigned u = __float_as_uint(f);
    u += 0x7FFFu + ((u >> 16) & 1u);
    return (unsigned short)(u >> 16);
}
static __device__ __forceinline__ float bf2f(unsigned short s) {
    return __uint_as_float((unsigned)s << 16);
}

// ---- mega kernel: blocks [0,NBLK1) partition edges; [NBLK1,..) do MFMA proj
__global__ __launch_bounds__(256) void mega_kernel(
    const float* __restrict__ x, const float* __restrict__ W,
    const int* __restrict__ ei, int* __restrict__ gcur, unsigned* __restrict__ gbuf,
    unsigned short* __restrict__ y1, unsigned short* __restrict__ y2)
{
    const int tid = threadIdx.x;
    const int lane = tid & 63;
    const int wv = tid >> 6;

    if (blockIdx.x < NBLK1) {
        // ---------------- partition by dst-bucket (LDS-staged) ----------------
        __shared__ int lcnt[NB];
        __shared__ int loff[NB + 1];
        __shared__ int lbase[NB];
        __shared__ int lcur[NB];
        __shared__ int wpart[4];
        __shared__ unsigned lbuf[EPB];
        __shared__ unsigned char lbkt[EPB];
        const int e0 = blockIdx.x * EPB;

        int rows[16], cols[16];
        #pragma unroll
        for (int j = 0; j < 16; ++j) {
            const int e = e0 + j * 256 + tid;
            const bool v = e < NE;
            rows[j] = v ? ei[e] : 0;
            cols[j] = v ? ei[NE + e] : -1;
        }
        for (int i = tid; i < NB; i += 256) lcnt[i] = 0;
        __syncthreads();
        #pragma unroll
        for (int j = 0; j < 16; ++j)
            if (cols[j] >= 0) atomicAdd(&lcnt[cols[j] >> 9], 1);
        __syncthreads();
        {   // block exclusive scan over NB bucket counts
            const int c = (tid < NB) ? lcnt[tid] : 0;
            int s = c;
            #pragma unroll
            for (int o = 1; o < 64; o <<= 1) { int t = __shfl_up(s, o); if (lane >= o) s += t; }
            if (lane == 63) wpart[wv] = s;
            __syncthreads();
            int woff = 0;
            for (int ww = 0; ww < wv; ++ww) woff += wpart[ww];
            if (tid < NB) {
                loff[tid] = woff + s - c;
                lcur[tid] = woff + s - c;
                lbase[tid] = atomicAdd(&gcur[tid], c);
            }
            if (tid == NB - 1) loff[NB] = woff + s;
        }
        __syncthreads();
        #pragma unroll
        for (int j = 0; j < 16; ++j) {
            if (cols[j] >= 0) {
                const int b = cols[j] >> 9;
                const int p = atomicAdd(&lcur[b], 1);
                lbuf[p] = ((unsigned)rows[j] << 9) | (unsigned)(cols[j] & (COLS - 1));
                lbkt[p] = (unsigned char)b;
            }
        }
        __syncthreads();
        const int total = loff[NB];
        for (int t = tid; t < total; t += 256) {   // ~21-word coalesced bursts
            const int b = lbkt[t];
            const unsigned idx = (unsigned)(lbase[b] + (t - loff[b]));
            if (idx < BSTRIDE) gbuf[(size_t)b * BSTRIDE + idx] = lbuf[t];
        }
    } else {
        // ---------------- [y1|y2] = x @ [W1|W2] via MFMA (m89 layouts) --------
        const int m = lane & 15;
        const int quad = lane >> 4;
        bf16x8 Wf[8][2];
        #pragma unroll
        for (int t = 0; t < 8; ++t)
            #pragma unroll
            for (int q = 0; q < 2; ++q) {
                bf16x8 f;
                #pragma unroll
                for (int j = 0; j < 8; ++j) {
                    const int k = q * 32 + quad * 8 + j;
                    const int krow = (t < 4) ? k : (64 + k);
                    const int col = (t & 3) * 16 + m;
                    f[j] = (short)f2bf(W[krow * 64 + col]);
                }
                Wf[t][q] = f;
            }
        for (int tile = (blockIdx.x - NBLK1) * 4 + wv; tile < NN / 16; tile += NPROJ * 4) {
            const int n0 = tile * 16;
            bf16x8 Af[2];
            #pragma unroll
            for (int q = 0; q < 2; ++q) {
                const float* px = x + (size_t)(n0 + m) * 64 + q * 32 + quad * 8;
                const f32x4 a0 = *(const f32x4*)px;
                const f32x4 a1 = *(const f32x4*)(px + 4);
                bf16x8 f;
                #pragma unroll
                for (int j = 0; j < 4; ++j) { f[j] = (short)f2bf(a0[j]); f[4 + j] = (short)f2bf(a1[j]); }
                Af[q] = f;
            }
            #pragma unroll
            for (int t = 0; t < 8; ++t) {
                f32x4 acc = {0.f, 0.f, 0.f, 0.f};
                acc = __builtin_amdgcn_mfma_f32_16x16x32_bf16(Af[0], Wf[t][0], acc, 0, 0, 0);
                acc = __builtin_amdgcn_mfma_f32_16x16x32_bf16(Af[1], Wf[t][1], acc, 0, 0, 0);
                unsigned short* __restrict__ dst = (t < 4) ? y1 : y2;
                const int colb = (t & 3) * 16 + m;
                #pragma unroll
                for (int r = 0; r < 4; ++r)
                    dst[(size_t)(n0 + quad * 4 + r) * 64 + colb] = f2bf(acc[r]);
            }
        }
    }
}

// ---- out: per quarter-bucket, build local CSR in LDS, gather, LN, store ----
__global__ __launch_bounds__(256) void out_kernel(
    const int* __restrict__ gcur, const unsigned* __restrict__ gbuf,
    const unsigned short* __restrict__ y1, const unsigned short* __restrict__ y2,
    const float* __restrict__ bias, const float* __restrict__ gamma,
    const float* __restrict__ beta, float* __restrict__ out)
{
    __shared__ int cofs[QCOLS];
    __shared__ int ccur[QCOLS];
    __shared__ int ldst[QCAP];
    const int tid = threadIdx.x;
    const int b = blockIdx.x >> 2;
    const int q = blockIdx.x & 3;
    const int qlo = q * QCOLS;
    const int cntE = min(gcur[b], BSTRIDE);
    const unsigned* __restrict__ gb = gbuf + (size_t)b * BSTRIDE;

    for (int i = tid; i < QCOLS; i += 256) cofs[i] = 0;
    __syncthreads();
    for (int i = tid; i < cntE; i += 256) {     // histogram my 128 cols
        const int c = (int)(gb[i] & (COLS - 1)) - qlo;
        if ((unsigned)c < QCOLS) atomicAdd(&cofs[c], 1);
    }
    __syncthreads();
    if (tid < 64) {   // single-wave exclusive scan of 128 counts (2/lane)
        const int v0 = cofs[tid * 2], v1 = cofs[tid * 2 + 1];
        const int tsum = v0 + v1;
        int s = tsum;
        #pragma unroll
        for (int o = 1; o < 64; o <<= 1) { int t = __shfl_up(s, o); if (tid >= o) s += t; }
        const int run = s - tsum;
        cofs[tid * 2] = run;     ccur[tid * 2] = run;
        cofs[tid * 2 + 1] = run + v0; ccur[tid * 2 + 1] = run + v0;
    }
    __syncthreads();
    for (int i = tid; i < cntE; i += 256) {     // place rows
        const unsigned p = gb[i];
        const int c = (int)(p & (COLS - 1)) - qlo;
        if ((unsigned)c < QCOLS) {
            const int pos = atomicAdd(&ccur[c], 1);
            if (pos < QCAP) ldst[pos] = (int)(p >> 9);
        }
    }
    __syncthreads();

    const int lane = tid & 63;
    const int wv = tid >> 6;
    const float bl = bias[lane], gl = gamma[lane], be = beta[lane];
    for (int j = 0; j < 32; ++j) {              // wave wv handles 32 nodes
        const int cloc = wv * 32 + j;
        const int n = b * COLS + qlo + cloc;
        if (n >= NN) break;
        const int s0 = cofs[cloc], s1 = min(ccur[cloc], QCAP);

        float acc = bf2f(y1[(size_t)n * OUT_D + lane]) + bl;
        int i = s0;
        for (; i + 4 <= s1; i += 4) {           // 4 gathers in flight
            const int r0 = ldst[i], r1 = ldst[i + 1], r2 = ldst[i + 2], r3 = ldst[i + 3];
            const float v0 = bf2f(y2[(size_t)r0 * OUT_D + lane]);
            const float v1 = bf2f(y2[(size_t)r1 * OUT_D + lane]);
            const float v2 = bf2f(y2[(size_t)r2 * OUT_D + lane]);
            const float v3 = bf2f(y2[(size_t)r3 * OUT_D + lane]);
            acc += (v0 + v1) + (v2 + v3);
        }
        for (; i < s1; ++i) acc += bf2f(y2[(size_t)ldst[i] * OUT_D + lane]);

        float sv = acc, sq = acc * acc;
        #pragma unroll
        for (int off = 32; off; off >>= 1) { sv += __shfl_xor(sv, off); sq += __shfl_xor(sq, off); }
        const float mu  = sv * (1.0f / OUT_D);
        const float var = sq * (1.0f / OUT_D) - mu * mu;
        const float inv = rsqrtf(var + EPS);
        out[(size_t)n * OUT_D + lane] = (acc - mu) * inv * gl + be;
    }
}

extern "C" void kernel_launch(void* const* d_in, const int* in_sizes, int n_in,
                              void* d_out, int out_size, void* d_ws, size_t ws_size,
                              hipStream_t stream) {
    const float* x     = (const float*)d_in[0];
    const int*   ei    = (const int*)  d_in[1];
    const float* W     = (const float*)d_in[2];
    const float* b     = (const float*)d_in[3];
    const float* gamma = (const float*)d_in[4];
    const float* beta  = (const float*)d_in[5];
    float* out = (float*)d_out;

    char* p = (char*)d_ws;
    int*            gcur = (int*)p;            p += 1024;
    unsigned*       gbuf = (unsigned*)p;       p += (size_t)NB * BSTRIDE * 4;   // 4.72 MB
    unsigned short* y1   = (unsigned short*)p; p += (size_t)NN * OUT_D * 2;     // 12.8 MB
    unsigned short* y2   = (unsigned short*)p;                                  // 12.8 MB

    hipMemsetAsync(gcur, 0, NB * sizeof(int), stream);
    mega_kernel<<<NBLK1 + NPROJ, 256, 0, stream>>>(x, W, ei, gcur, gbuf, y1, y2);
    out_kernel <<<NB * 4, 256, 0, stream>>>(gcur, gbuf, y1, y2, b, gamma, beta, out);
}

// Round 7
// 150.076 us; speedup vs baseline: 1.2200x; 1.2200x over previous
//
#include <hip/hip_runtime.h>

#define NN 100000
#define NE 1000000
#define OUT_D 64
#define EPS 1e-5f

#define NB 196         // buckets of 512 destination cols: 196*512 = 100352 >= NN
#define COLS 512
#define BSTRIDE 6016   // per-bucket capacity: mean 5120, +12.6 sigma
#define EPB 4096       // edges per part-block
#define NBLK1 245      // part blocks = ceil(NE/EPB)
#define NPROJ 1024     // proj blocks fused behind part

typedef __attribute__((ext_vector_type(8))) short bf16x8;
typedef __attribute__((ext_vector_type(4))) float f32x4;

static __device__ __forceinline__ unsigned short f2bf(float f) {   // RNE
    unsigned u = __float_as_uint(f);
    u += 0x7FFFu + ((u >> 16) & 1u);
    return (unsigned short)(u >> 16);
}
static __device__ __forceinline__ float bf2f(unsigned short s) {
    return __uint_as_float((unsigned)s << 16);
}

// ---- mega kernel: blocks [0,NBLK1) partition edges; [NBLK1,..) do MFMA proj
__global__ __launch_bounds__(256) void mega_kernel(
    const float* __restrict__ x, const float* __restrict__ W,
    const int* __restrict__ ei, int* __restrict__ gcur, unsigned* __restrict__ gbuf,
    unsigned short* __restrict__ y1, unsigned short* __restrict__ y2)
{
    const int tid = threadIdx.x;
    const int lane = tid & 63;
    const int wv = tid >> 6;

    if (blockIdx.x < NBLK1) {
        // ---------------- partition by dst-bucket (LDS-staged) ----------------
        __shared__ int lcnt[NB];
        __shared__ int loff[NB + 1];
        __shared__ int lbase[NB];
        __shared__ int lcur[NB];
        __shared__ int wpart[4];
        __shared__ unsigned lbuf[EPB];
        __shared__ unsigned char lbkt[EPB];
        const int e0 = blockIdx.x * EPB;

        int rows[16], cols[16];
        #pragma unroll
        for (int j = 0; j < 16; ++j) {
            const int e = e0 + j * 256 + tid;
            const bool v = e < NE;
            rows[j] = v ? ei[e] : 0;
            cols[j] = v ? ei[NE + e] : -1;
        }
        for (int i = tid; i < NB; i += 256) lcnt[i] = 0;
        __syncthreads();
        #pragma unroll
        for (int j = 0; j < 16; ++j)
            if (cols[j] >= 0) atomicAdd(&lcnt[cols[j] >> 9], 1);
        __syncthreads();
        {   // block exclusive scan over NB bucket counts
            const int c = (tid < NB) ? lcnt[tid] : 0;
            int s = c;
            #pragma unroll
            for (int o = 1; o < 64; o <<= 1) { int t = __shfl_up(s, o); if (lane >= o) s += t; }
            if (lane == 63) wpart[wv] = s;
            __syncthreads();
            int woff = 0;
            for (int ww = 0; ww < wv; ++ww) woff += wpart[ww];
            if (tid < NB) {
                loff[tid] = woff + s - c;
                lcur[tid] = woff + s - c;
                lbase[tid] = atomicAdd(&gcur[tid], c);
            }
            if (tid == NB - 1) loff[NB] = woff + s;
        }
        __syncthreads();
        #pragma unroll
        for (int j = 0; j < 16; ++j) {
            if (cols[j] >= 0) {
                const int b = cols[j] >> 9;
                const int p = atomicAdd(&lcur[b], 1);
                lbuf[p] = ((unsigned)rows[j] << 9) | (unsigned)(cols[j] & (COLS - 1));
                lbkt[p] = (unsigned char)b;
            }
        }
        __syncthreads();
        const int total = loff[NB];
        for (int t = tid; t < total; t += 256) {   // ~21-word coalesced bursts
            const int b = lbkt[t];
            const unsigned idx = (unsigned)(lbase[b] + (t - loff[b]));
            if (idx < BSTRIDE) gbuf[(size_t)b * BSTRIDE + idx] = lbuf[t];
        }
    } else {
        // ---------------- [y1|y2] = x @ [W1|W2] via MFMA (m89 layouts) --------
        const int m = lane & 15;
        const int quad = lane >> 4;
        bf16x8 Wf[8][2];
        #pragma unroll
        for (int t = 0; t < 8; ++t)
            #pragma unroll
            for (int q = 0; q < 2; ++q) {
                bf16x8 f;
                #pragma unroll
                for (int j = 0; j < 8; ++j) {
                    const int k = q * 32 + quad * 8 + j;
                    const int krow = (t < 4) ? k : (64 + k);
                    const int col = (t & 3) * 16 + m;
                    f[j] = (short)f2bf(W[krow * 64 + col]);
                }
                Wf[t][q] = f;
            }
        for (int tile = (blockIdx.x - NBLK1) * 4 + wv; tile < NN / 16; tile += NPROJ * 4) {
            const int n0 = tile * 16;
            bf16x8 Af[2];
            #pragma unroll
            for (int q = 0; q < 2; ++q) {
                const float* px = x + (size_t)(n0 + m) * 64 + q * 32 + quad * 8;
                const f32x4 a0 = *(const f32x4*)px;
                const f32x4 a1 = *(const f32x4*)(px + 4);
                bf16x8 f;
                #pragma unroll
                for (int j = 0; j < 4; ++j) { f[j] = (short)f2bf(a0[j]); f[4 + j] = (short)f2bf(a1[j]); }
                Af[q] = f;
            }
            #pragma unroll
            for (int t = 0; t < 8; ++t) {
                f32x4 acc = {0.f, 0.f, 0.f, 0.f};
                acc = __builtin_amdgcn_mfma_f32_16x16x32_bf16(Af[0], Wf[t][0], acc, 0, 0, 0);
                acc = __builtin_amdgcn_mfma_f32_16x16x32_bf16(Af[1], Wf[t][1], acc, 0, 0, 0);
                unsigned short* __restrict__ dst = (t < 4) ? y1 : y2;
                const int colb = (t & 3) * 16 + m;
                #pragma unroll
                for (int r = 0; r < 4; ++r)
                    dst[(size_t)(n0 + quad * 4 + r) * 64 + colb] = f2bf(acc[r]);
            }
        }
    }
}

// ---------------- per-bucket CSR build (LDS), exact rowptr ----------------
__global__ __launch_bounds__(256) void place_kernel(
    const int* __restrict__ gcur, const unsigned* __restrict__ gbuf,
    int* __restrict__ csr, int* __restrict__ rowptr)
{
    __shared__ int cofs[COLS];
    __shared__ int ccur[COLS];
    __shared__ int sbase[2];
    __shared__ unsigned lsrc[BSTRIDE];
    __shared__ unsigned ldst[BSTRIDE];
    const int b = blockIdx.x, tid = threadIdx.x;
    const int n0 = b << 9;

    if (tid < 64) {   // base = sum of bucket counts before b
        int partial = 0;
        for (int i = tid; i < b; i += 64) partial += gcur[i];
        #pragma unroll
        for (int o = 32; o; o >>= 1) partial += __shfl_xor(partial, o);
        if (tid == 0) { sbase[0] = partial; sbase[1] = min(gcur[b], BSTRIDE); }
    }
    for (int i = tid; i < COLS; i += 256) cofs[i] = 0;
    __syncthreads();
    const int base = sbase[0], cntE = sbase[1];
    const unsigned* __restrict__ gb = gbuf + (size_t)b * BSTRIDE;

    for (int i = tid; i < cntE; i += 256) {    // stage + histogram
        const unsigned p = gb[i];
        lsrc[i] = p;
        atomicAdd(&cofs[p & (COLS - 1)], 1);
    }
    __syncthreads();
    if (tid < 64) {   // single-wave exclusive scan of 512 counts (8/lane)
        int v[8], tsum = 0;
        #pragma unroll
        for (int k = 0; k < 8; ++k) { v[k] = cofs[tid * 8 + k]; tsum += v[k]; }
        int s = tsum;
        #pragma unroll
        for (int o = 1; o < 64; o <<= 1) { int t = __shfl_up(s, o); if (tid >= o) s += t; }
        int run = s - tsum;
        #pragma unroll
        for (int k = 0; k < 8; ++k) { cofs[tid * 8 + k] = run; ccur[tid * 8 + k] = run; run += v[k]; }
    }
    __syncthreads();
    for (int i = tid; i < cntE; i += 256) {    // place rows (LDS scatter)
        const unsigned p = lsrc[i];
        const int pos = atomicAdd(&ccur[p & (COLS - 1)], 1);
        ldst[pos] = p >> 9;
    }
    __syncthreads();
    for (int i = tid; i < cntE; i += 256) csr[base + i] = (int)ldst[i];  // coalesced
    const int ncols = min(COLS, NN - n0);
    for (int c = tid; c < ncols; c += 256) rowptr[n0 + c] = base + cofs[c];
    if (b == NB - 1 && tid == 0) rowptr[NN] = base + cntE;
}

// ---- out: one node per wave (100K waves), gather(y2) + y1 + bias, LN ------
__global__ __launch_bounds__(256) void out_kernel(
    const int* __restrict__ rowptr, const int* __restrict__ csr,
    const unsigned short* __restrict__ y1, const unsigned short* __restrict__ y2,
    const float* __restrict__ bias, const float* __restrict__ gamma,
    const float* __restrict__ beta, float* __restrict__ out)
{
    const int lane = threadIdx.x & 63;
    const int n = __builtin_amdgcn_readfirstlane(blockIdx.x * 4 + (threadIdx.x >> 6));
    const int s0 = rowptr[n], s1 = rowptr[n + 1];

    float acc = bf2f(y1[(size_t)n * OUT_D + lane]) + bias[lane];
    int i = s0;
    for (; i + 4 <= s1; i += 4) {              // 4 gathers in flight
        const int r0 = csr[i], r1 = csr[i + 1], r2 = csr[i + 2], r3 = csr[i + 3];
        const float v0 = bf2f(y2[(size_t)r0 * OUT_D + lane]);
        const float v1 = bf2f(y2[(size_t)r1 * OUT_D + lane]);
        const float v2 = bf2f(y2[(size_t)r2 * OUT_D + lane]);
        const float v3 = bf2f(y2[(size_t)r3 * OUT_D + lane]);
        acc += (v0 + v1) + (v2 + v3);
    }
    for (; i < s1; ++i) acc += bf2f(y2[(size_t)csr[i] * OUT_D + lane]);

    float sv = acc, sq = acc * acc;
    #pragma unroll
    for (int off = 32; off; off >>= 1) { sv += __shfl_xor(sv, off); sq += __shfl_xor(sq, off); }
    const float mu  = sv * (1.0f / OUT_D);
    const float var = sq * (1.0f / OUT_D) - mu * mu;
    const float inv = rsqrtf(var + EPS);
    out[(size_t)n * OUT_D + lane] = (acc - mu) * inv * gamma[lane] + beta[lane];
}

extern "C" void kernel_launch(void* const* d_in, const int* in_sizes, int n_in,
                              void* d_out, int out_size, void* d_ws, size_t ws_size,
                              hipStream_t stream) {
    const float* x     = (const float*)d_in[0];
    const int*   ei    = (const int*)  d_in[1];
    const float* W     = (const float*)d_in[2];
    const float* b     = (const float*)d_in[3];
    const float* gamma = (const float*)d_in[4];
    const float* beta  = (const float*)d_in[5];
    float* out = (float*)d_out;

    char* p = (char*)d_ws;
    int*            gcur   = (int*)p;             p += 1024;
    unsigned*       gbuf   = (unsigned*)p;        p += (size_t)NB * BSTRIDE * 4;   // 4.72 MB
    int*            csr    = (int*)p;             p += (size_t)NE * 4;             // 4 MB
    int*            rowptr = (int*)p;             p += (NB * COLS + 64) * 4;       // 0.4 MB
    unsigned short* y1     = (unsigned short*)p;  p += (size_t)NN * OUT_D * 2;     // 12.8 MB
    unsigned short* y2     = (unsigned short*)p;                                   // 12.8 MB

    hipMemsetAsync(gcur, 0, NB * sizeof(int), stream);
    mega_kernel <<<NBLK1 + NPROJ, 256, 0, stream>>>(x, W, ei, gcur, gbuf, y1, y2);
    place_kernel<<<NB, 256, 0, stream>>>(gcur, gbuf, csr, rowptr);
    out_kernel  <<<NN / 4, 256, 0, stream>>>(rowptr, csr, y1, y2, b, gamma, beta, out);
}

// Round 8
// 143.392 us; speedup vs baseline: 1.2769x; 1.0466x over previous
//
#include <hip/hip_runtime.h>

#define NN 100000
#define NE 1000000
#define OUT_D 64
#define EPS 1e-5f

#define NB 196          // buckets of 512 destination cols: 196*512 = 100352 >= NN
#define COLS 512
#define BSTRIDE 6016    // per-bucket raw capacity: mean 5120, +12.6 sigma
#define PBSTRIDE 8064   // padded capacity: BSTRIDE + 4*COLS/... (mult of 4)
#define EPB 4096        // edges per part-block
#define NBLK1 245       // part blocks = ceil(NE/EPB)
#define NPROJ 1024      // proj blocks fused behind part

typedef __attribute__((ext_vector_type(8))) short bf16x8;
typedef __attribute__((ext_vector_type(4))) float f32x4;
typedef __attribute__((ext_vector_type(4))) int i32x4;

static __device__ __forceinline__ unsigned short f2bf(float f) {   // RNE
    unsigned u = __float_as_uint(f);
    u += 0x7FFFu + ((u >> 16) & 1u);
    return (unsigned short)(u >> 16);
}
static __device__ __forceinline__ float bf2f(unsigned short s) {
    return __uint_as_float((unsigned)s << 16);
}

// ---- mega kernel: blocks [0,NBLK1) partition edges; [NBLK1,..) do MFMA proj
__global__ __launch_bounds__(256) void mega_kernel(
    const float* __restrict__ x, const float* __restrict__ W,
    const int* __restrict__ ei, int* __restrict__ gcur, unsigned* __restrict__ gbuf,
    unsigned short* __restrict__ y1, unsigned short* __restrict__ y2)
{
    const int tid = threadIdx.x;
    const int lane = tid & 63;
    const int wv = tid >> 6;

    if (blockIdx.x < NBLK1) {
        // ---------------- partition by dst-bucket (LDS-staged) ----------------
        __shared__ int lcnt[NB];
        __shared__ int loff[NB + 1];
        __shared__ int lbase[NB];
        __shared__ int lcur[NB];
        __shared__ int wpart[4];
        __shared__ unsigned lbuf[EPB];
        __shared__ unsigned char lbkt[EPB];
        const int e0 = blockIdx.x * EPB;

        int rows[16], cols[16];
        #pragma unroll
        for (int j = 0; j < 16; ++j) {
            const int e = e0 + j * 256 + tid;
            const bool v = e < NE;
            rows[j] = v ? ei[e] : 0;
            cols[j] = v ? ei[NE + e] : -1;
        }
        for (int i = tid; i < NB; i += 256) lcnt[i] = 0;
        __syncthreads();
        #pragma unroll
        for (int j = 0; j < 16; ++j)
            if (cols[j] >= 0) atomicAdd(&lcnt[cols[j] >> 9], 1);
        __syncthreads();
        {   // block exclusive scan over NB bucket counts
            const int c = (tid < NB) ? lcnt[tid] : 0;
            int s = c;
            #pragma unroll
            for (int o = 1; o < 64; o <<= 1) { int t = __shfl_up(s, o); if (lane >= o) s += t; }
            if (lane == 63) wpart[wv] = s;
            __syncthreads();
            int woff = 0;
            for (int ww = 0; ww < wv; ++ww) woff += wpart[ww];
            if (tid < NB) {
                loff[tid] = woff + s - c;
                lcur[tid] = woff + s - c;
                lbase[tid] = atomicAdd(&gcur[tid], c);
            }
            if (tid == NB - 1) loff[NB] = woff + s;
        }
        __syncthreads();
        #pragma unroll
        for (int j = 0; j < 16; ++j) {
            if (cols[j] >= 0) {
                const int b = cols[j] >> 9;
                const int p = atomicAdd(&lcur[b], 1);
                lbuf[p] = ((unsigned)rows[j] << 9) | (unsigned)(cols[j] & (COLS - 1));
                lbkt[p] = (unsigned char)b;
            }
        }
        __syncthreads();
        const int total = loff[NB];
        for (int t = tid; t < total; t += 256) {   // ~21-word coalesced bursts
            const int b = lbkt[t];
            const unsigned idx = (unsigned)(lbase[b] + (t - loff[b]));
            if (idx < BSTRIDE) gbuf[(size_t)b * BSTRIDE + idx] = lbuf[t];
        }
    } else {
        // ---------------- [y1|y2] = x @ [W1|W2] via MFMA (m89 layouts) --------
        const int m = lane & 15;
        const int quad = lane >> 4;
        bf16x8 Wf[8][2];
        #pragma unroll
        for (int t = 0; t < 8; ++t)
            #pragma unroll
            for (int q = 0; q < 2; ++q) {
                bf16x8 f;
                #pragma unroll
                for (int j = 0; j < 8; ++j) {
                    const int k = q * 32 + quad * 8 + j;
                    const int krow = (t < 4) ? k : (64 + k);
                    const int col = (t & 3) * 16 + m;
                    f[j] = (short)f2bf(W[krow * 64 + col]);
                }
                Wf[t][q] = f;
            }
        for (int tile = (blockIdx.x - NBLK1) * 4 + wv; tile < NN / 16; tile += NPROJ * 4) {
            const int n0 = tile * 16;
            bf16x8 Af[2];
            #pragma unroll
            for (int q = 0; q < 2; ++q) {
                const float* px = x + (size_t)(n0 + m) * 64 + q * 32 + quad * 8;
                const f32x4 a0 = *(const f32x4*)px;
                const f32x4 a1 = *(const f32x4*)(px + 4);
                bf16x8 f;
                #pragma unroll
                for (int j = 0; j < 4; ++j) { f[j] = (short)f2bf(a0[j]); f[4 + j] = (short)f2bf(a1[j]); }
                Af[q] = f;
            }
            #pragma unroll
            for (int t = 0; t < 8; ++t) {
                f32x4 acc = {0.f, 0.f, 0.f, 0.f};
                acc = __builtin_amdgcn_mfma_f32_16x16x32_bf16(Af[0], Wf[t][0], acc, 0, 0, 0);
                acc = __builtin_amdgcn_mfma_f32_16x16x32_bf16(Af[1], Wf[t][1], acc, 0, 0, 0);
                unsigned short* __restrict__ dst = (t < 4) ? y1 : y2;
                const int colb = (t & 3) * 16 + m;
                #pragma unroll
                for (int r = 0; r < 4; ++r)
                    dst[(size_t)(n0 + quad * 4 + r) * 64 + colb] = f2bf(acc[r]);
            }
        }
    }
}

// ---- per-bucket padded CSR build: segments 4-aligned, pads -> row NN ------
__global__ __launch_bounds__(256) void place_kernel(
    const int* __restrict__ gcur, const unsigned* __restrict__ gbuf,
    int* __restrict__ csr, unsigned* __restrict__ rowpack,
    unsigned short* __restrict__ y2)
{
    __shared__ int cofs[COLS + 1];   // padded exclusive scan (inclusive at end)
    __shared__ int ccur[COLS];
    __shared__ unsigned lsrc[BSTRIDE];
    __shared__ int ldst[PBSTRIDE];
    const int b = blockIdx.x, tid = threadIdx.x;
    const int n0 = b << 9;

    if (b == 0 && tid < 64) y2[(size_t)NN * OUT_D + tid] = 0;   // zeros row

    for (int i = tid; i < COLS; i += 256) cofs[i] = 0;
    for (int i = tid; i < PBSTRIDE; i += 256) ldst[i] = NN;     // pad = zeros row
    __syncthreads();
    const int cntE = min(gcur[b], BSTRIDE);
    const unsigned* __restrict__ gb = gbuf + (size_t)b * BSTRIDE;

    for (int i = tid; i < cntE; i += 256) {    // stage + histogram
        const unsigned p = gb[i];
        lsrc[i] = p;
        atomicAdd(&cofs[p & (COLS - 1)], 1);
    }
    __syncthreads();
    if (tid < 64) {   // single-wave exclusive scan of 512 PADDED counts (8/lane)
        int v[8], tsum = 0;
        #pragma unroll
        for (int k = 0; k < 8; ++k) { v[k] = (cofs[tid * 8 + k] + 3) & ~3; tsum += v[k]; }
        int s = tsum;
        #pragma unroll
        for (int o = 1; o < 64; o <<= 1) { int t = __shfl_up(s, o); if (tid >= o) s += t; }
        int run = s - tsum;
        #pragma unroll
        for (int k = 0; k < 8; ++k) { cofs[tid * 8 + k] = run; ccur[tid * 8 + k] = run; run += v[k]; }
        if (tid == 63) cofs[COLS] = run;
    }
    __syncthreads();
    for (int i = tid; i < cntE; i += 256) {    // place rows (LDS scatter)
        const unsigned p = lsrc[i];
        const int pos = atomicAdd(&ccur[p & (COLS - 1)], 1);
        ldst[pos] = (int)(p >> 9);
    }
    __syncthreads();
    const int ptotal = cofs[COLS];
    const int base = b * PBSTRIDE;
    for (int i = tid; i < ptotal; i += 256) csr[base + i] = ldst[i];   // coalesced
    const int ncols = min(COLS, NN - n0);
    for (int c = tid; c < ncols; c += 256) {
        const int st = cofs[c];
        const int len = min(cofs[c + 1] - st, 511);
        rowpack[n0 + c] = ((unsigned)st << 9) | (unsigned)len;
    }
}

// ---- out: one node per wave; padded csr (dwordx4), 8 gathers in flight ----
__global__ __launch_bounds__(256) void out_kernel(
    const unsigned* __restrict__ rowpack, const int* __restrict__ csr,
    const unsigned short* __restrict__ y1, const unsigned short* __restrict__ y2,
    const float* __restrict__ bias, const float* __restrict__ gamma,
    const float* __restrict__ beta, float* __restrict__ out)
{
    const int lane = threadIdx.x & 63;
    const int n = __builtin_amdgcn_readfirstlane(blockIdx.x * 4 + (threadIdx.x >> 6));
    const unsigned pk = rowpack[n];
    const int cnt = (int)(pk & 511);                       // multiple of 4
    const i32x4* __restrict__ cs =
        (const i32x4*)(csr + (n >> 9) * PBSTRIDE + (int)(pk >> 9));

    float acc = bf2f(y1[(size_t)n * OUT_D + lane]) + bias[lane];
    int i = 0;
    for (; i + 8 <= cnt; i += 8) {                         // 8 gathers in flight
        const i32x4 c0 = cs[(i >> 2)];
        const i32x4 c1 = cs[(i >> 2) + 1];
        const float v0 = bf2f(y2[(size_t)c0[0] * OUT_D + lane]);
        const float v1 = bf2f(y2[(size_t)c0[1] * OUT_D + lane]);
        const float v2 = bf2f(y2[(size_t)c0[2] * OUT_D + lane]);
        const float v3 = bf2f(y2[(size_t)c0[3] * OUT_D + lane]);
        const float v4 = bf2f(y2[(size_t)c1[0] * OUT_D + lane]);
        const float v5 = bf2f(y2[(size_t)c1[1] * OUT_D + lane]);
        const float v6 = bf2f(y2[(size_t)c1[2] * OUT_D + lane]);
        const float v7 = bf2f(y2[(size_t)c1[3] * OUT_D + lane]);
        acc += ((v0 + v1) + (v2 + v3)) + ((v4 + v5) + (v6 + v7));
    }
    if (i < cnt) {                                         // exactly 4 left
        const i32x4 c0 = cs[(i >> 2)];
        const float v0 = bf2f(y2[(size_t)c0[0] * OUT_D + lane]);
        const float v1 = bf2f(y2[(size_t)c0[1] * OUT_D + lane]);
        const float v2 = bf2f(y2[(size_t)c0[2] * OUT_D + lane]);
        const float v3 = bf2f(y2[(size_t)c0[3] * OUT_D + lane]);
        acc += (v0 + v1) + (v2 + v3);
    }

    float sv = acc, sq = acc * acc;
    #pragma unroll
    for (int off = 32; off; off >>= 1) { sv += __shfl_xor(sv, off); sq += __shfl_xor(sq, off); }
    const float mu  = sv * (1.0f / OUT_D);
    const float var = sq * (1.0f / OUT_D) - mu * mu;
    const float inv = rsqrtf(var + EPS);
    out[(size_t)n * OUT_D + lane] = (acc - mu) * inv * gamma[lane] + beta[lane];
}

extern "C" void kernel_launch(void* const* d_in, const int* in_sizes, int n_in,
                              void* d_out, int out_size, void* d_ws, size_t ws_size,
                              hipStream_t stream) {
    const float* x     = (const float*)d_in[0];
    const int*   ei    = (const int*)  d_in[1];
    const float* W     = (const float*)d_in[2];
    const float* b     = (const float*)d_in[3];
    const float* gamma = (const float*)d_in[4];
    const float* beta  = (const float*)d_in[5];
    float* out = (float*)d_out;

    char* p = (char*)d_ws;
    int*            gcur    = (int*)p;             p += 1024;
    unsigned*       gbuf    = (unsigned*)p;        p += (size_t)NB * BSTRIDE * 4;   // 4.72 MB
    int*            csr     = (int*)p;             p += (size_t)NB * PBSTRIDE * 4;  // 6.32 MB
    unsigned*       rowpack = (unsigned*)p;        p += (size_t)(NB * COLS) * 4;    // 0.4 MB
    unsigned short* y1      = (unsigned short*)p;  p += (size_t)NN * OUT_D * 2;     // 12.8 MB
    unsigned short* y2      = (unsigned short*)p;                                   // 12.8 MB + pad row

    hipMemsetAsync(gcur, 0, NB * sizeof(int), stream);
    mega_kernel <<<NBLK1 + NPROJ, 256, 0, stream>>>(x, W, ei, gcur, gbuf, y1, y2);
    place_kernel<<<NB, 256, 0, stream>>>(gcur, gbuf, csr, rowpack, y2);
    out_kernel  <<<NN / 4, 256, 0, stream>>>(rowpack, csr, y1, y2, b, gamma, beta, out);
}